// Round 2
// baseline (196.401 us; speedup 1.0000x reference)
//
#include <hip/hip_runtime.h>
#include <stdint.h>

#define NNODE   17
#define FDIM    64
#define GPB     16                  // graphs per chunk
#define ROWS    (GPB*NNODE)         // 272
#define LDK     136                 // padded K stride in bf16 elems (128 + 8 -> conflict-free b128)
#define NBLOCK  512
#define ITERS   8                   // 512*8*16 = 65536 graphs

typedef __attribute__((ext_vector_type(8))) short short8;
typedef __attribute__((ext_vector_type(4))) float f32x4;

__device__ __forceinline__ uint32_t bf16b(float f) {
    uint32_t u = __float_as_uint(f);
    return (u + 0x7fffu + ((u >> 16) & 1u)) >> 16;   // round-to-nearest-even
}
__device__ __forceinline__ uint32_t bfpack(float lo, float hi) {
    return bf16b(lo) | (bf16b(hi) << 16);
}

__global__ __launch_bounds__(256) void egc_kernel(
    const float* __restrict__ x, const float* __restrict__ adj,
    const float* __restrict__ wself, const float* __restrict__ wneigh,
    const float* __restrict__ bias, float* __restrict__ out)
{
    // XZ: 272 rows x [x(64) | z(64)] bf16, padded stride 136 (272B rows: bank-spread for b128)
    __shared__ uint16_t sXZ[ROWS][LDK];       // 73984 B
    __shared__ float sAdj[NNODE * NNODE];
    __shared__ float sBias[FDIM];

    const int t    = threadIdx.x;
    const int lane = t & 63;
    const int wv   = t >> 6;          // wave id == output col-tile (16 cols each)
    const int lr   = lane & 15;
    const int lh   = lane >> 4;

    // ---- once per block: stage W2T[o][k] (k<64: Ws[k][o], k>=64: Wn[k-64][o]) into sXZ area
    for (int idx = t; idx < FDIM * 128; idx += 256) {
        int o = idx >> 7, k = idx & 127;
        float v = (k < 64) ? wself[k * 64 + o] : wneigh[(k - 64) * 64 + o];
        sXZ[o][k] = (uint16_t)bf16b(v);
    }
    for (int i = t; i < NNODE * NNODE; i += 256) sAdj[i] = adj[i];   // 289 > 256: strided!
    if (t < FDIM) sBias[t] = bias[t];
    __syncthreads();

    // B-frags for this wave's col-tile: lane l holds B[k=32q+8*lh+e][n=16*wv+lr]
    short8 bfrag[4];
    #pragma unroll
    for (int q = 0; q < 4; ++q)
        bfrag[q] = *(const short8*)&sXZ[16 * wv + lr][32 * q + 8 * lh];
    const float breg = sBias[16 * wv + lr];
    __syncthreads();

    for (int it = 0; it < ITERS; ++it) {
        const int chunk = blockIdx.x * ITERS + it;

        // ---- P1: global x (fp32, coalesced float4) -> bf16 LDS cols 0..63
        const float4* xg = (const float4*)(x + (size_t)chunk * (ROWS * FDIM));
        #pragma unroll
        for (int j = 0; j < 17; ++j) {            // 4352 float4 / 256 thr
            int idx = t + j * 256;
            float4 v = xg[idx];
            int row = idx >> 4, c4 = (idx & 15) << 2;
            *(uint32_t*)&sXZ[row][c4]     = bfpack(v.x, v.y);
            *(uint32_t*)&sXZ[row][c4 + 2] = bfpack(v.z, v.w);
        }
        __syncthreads();

        // ---- P2: z[g,n,i] = sum_m adj[n,m] * x[g,m,i] -> bf16 LDS cols 64..127
        {
            const int i4 = (t & 15) << 2;         // i offset (4 wide)
            const int g  = t >> 4;                // graph 0..15
            float xf[NNODE][4];
            #pragma unroll
            for (int m = 0; m < NNODE; ++m) {
                uint2 p = *(const uint2*)&sXZ[g * NNODE + m][i4];
                xf[m][0] = __uint_as_float(p.x << 16);
                xf[m][1] = __uint_as_float(p.x & 0xffff0000u);
                xf[m][2] = __uint_as_float(p.y << 16);
                xf[m][3] = __uint_as_float(p.y & 0xffff0000u);
            }
            for (int n = 0; n < NNODE; ++n) {
                float a0 = 0.f, a1 = 0.f, a2 = 0.f, a3 = 0.f;
                #pragma unroll
                for (int m = 0; m < NNODE; ++m) {
                    float w = sAdj[n * NNODE + m];
                    a0 += w * xf[m][0]; a1 += w * xf[m][1];
                    a2 += w * xf[m][2]; a3 += w * xf[m][3];
                }
                uint2 pz; pz.x = bfpack(a0, a1); pz.y = bfpack(a2, a3);
                *(uint2*)&sXZ[g * NNODE + n][64 + i4] = pz;
            }
        }
        __syncthreads();

        // ---- P3: out = [x|z] @ [Ws;Wn] + bias ; 17 row-tiles, wave=col-tile
        {
            float* outg = out + (size_t)chunk * (ROWS * FDIM);
            #pragma unroll 2
            for (int rt = 0; rt < 17; ++rt) {
                f32x4 acc = { breg, breg, breg, breg };
                #pragma unroll
                for (int q = 0; q < 4; ++q) {
                    // A: lane l holds A[m=lr][k=32q+8*lh+e] (8 consecutive bf16 -> b128)
                    short8 af = *(const short8*)&sXZ[rt * 16 + lr][32 * q + 8 * lh];
                    acc = __builtin_amdgcn_mfma_f32_16x16x32_bf16(af, bfrag[q], acc, 0, 0, 0);
                }
                // D: lane l holds D[row=4*lh+r][col=lr] (m89-verified layout)
                const int rbase = rt * 16 + 4 * lh;
                #pragma unroll
                for (int r = 0; r < 4; ++r)
                    outg[(rbase + r) * 64 + 16 * wv + lr] = acc[r];
            }
        }
        __syncthreads();
    }
}

extern "C" void kernel_launch(void* const* d_in, const int* in_sizes, int n_in,
                              void* d_out, int out_size, void* d_ws, size_t ws_size,
                              hipStream_t stream) {
    (void)in_sizes; (void)n_in; (void)d_ws; (void)ws_size; (void)out_size;
    const float* x      = (const float*)d_in[0];
    const float* adj    = (const float*)d_in[1];
    const float* wself  = (const float*)d_in[2];
    const float* wneigh = (const float*)d_in[3];
    const float* bias   = (const float*)d_in[4];
    float* out = (float*)d_out;
    egc_kernel<<<NBLOCK, 256, 0, stream>>>(x, adj, wself, wneigh, bias, out);
}